// Round 7
// baseline (5903.189 us; speedup 1.0000x reference)
//
#include <hip/hip_runtime.h>
#include <hip/hip_bf16.h>

#define BATCH 128
#define SEQ   1024
#define INDIM 256
#define HID   1024
#define NGATE 4096   // 4*HID
#define KTOT  1280   // INDIM + HID
#define OUTD  256
#define NKK   40     // total K-steps of 32 (1280/32)
#define XKK   8      // k-steps covering the x part (256/32)
#define HKK   32     // k-steps covering the h part
#define NBG   8      // batch groups
#define ROWS  16     // batch rows per group
#define NSL   32     // WGs per group
#define JCOLS 32     // h-columns per WG

typedef __attribute__((ext_vector_type(8))) short s16x8;
typedef __attribute__((ext_vector_type(4))) float f32x4;

__device__ __forceinline__ unsigned short f2bf(float f) {
    unsigned int u = __float_as_uint(f);
    u += 0x7FFFu + ((u >> 16) & 1u);
    return (unsigned short)(u >> 16);
}
__device__ __forceinline__ float sigmoidf_(float x) {
    return 1.0f / (1.0f + __expf(-x));
}
__device__ __forceinline__ float tanhf_(float x) {
    return 1.0f - 2.0f / (1.0f + __expf(2.0f * x));
}

// ---------------------------------------------------------------------------
// Prep 1: WT[n][k] bf16 (transposed, concatenated [Wx;Wh])
// ---------------------------------------------------------------------------
__global__ __launch_bounds__(256) void prep_wt(const float* __restrict__ Wx,
                                               const float* __restrict__ Wh,
                                               unsigned short* __restrict__ WT) {
    __shared__ float tile[64][65];
    int k0 = blockIdx.x * 64;
    int n0 = blockIdx.y * 64;
    for (int idx = threadIdx.x; idx < 64 * 64; idx += 256) {
        int kk = idx >> 6, nn = idx & 63;
        int k = k0 + kk;
        float v = (k < INDIM) ? Wx[(size_t)k * NGATE + (n0 + nn)]
                              : Wh[(size_t)(k - INDIM) * NGATE + (n0 + nn)];
        tile[kk][nn] = v;
    }
    __syncthreads();
    for (int idx = threadIdx.x; idx < 64 * 64; idx += 256) {
        int nn = idx >> 6, kk = idx & 63;
        WT[(size_t)(n0 + nn) * KTOT + (k0 + kk)] = f2bf(tile[kk][nn]);
    }
}

// ---------------------------------------------------------------------------
// Prep 2: x fp32 -> bf16; zero h0/h1; zero per-wave flags.
// ---------------------------------------------------------------------------
__global__ __launch_bounds__(256) void prep_x(const float* __restrict__ x,
                                              unsigned short* __restrict__ xb,
                                              unsigned short* __restrict__ h0,
                                              unsigned short* __restrict__ h1,
                                              unsigned int* __restrict__ flags) {
    int gid = blockIdx.x * blockDim.x + threadIdx.x;
    int stride = gridDim.x * blockDim.x;
    const int N4 = BATCH * SEQ * INDIM / 4;
    const float4* xv = reinterpret_cast<const float4*>(x);
    uint2* xo = reinterpret_cast<uint2*>(xb);
    for (int i = gid; i < N4; i += stride) {
        float4 v = xv[i];
        uint2 o;
        o.x = (unsigned)f2bf(v.x) | ((unsigned)f2bf(v.y) << 16);
        o.y = (unsigned)f2bf(v.z) | ((unsigned)f2bf(v.w) << 16);
        xo[i] = o;
    }
    const int NH = BATCH * HID;
    for (int i = gid; i < NH; i += stride) {
        h0[i] = 0;
        h1[i] = 0;
    }
    // flags: 256 WG x 8 waves x 16 uints (64B padded) = 32768 uints
    for (int i = gid; i < 32768; i += stride) flags[i] = 0;
}

// ---------------------------------------------------------------------------
// Persistent LSTM: 256 WGs x 512 threads (8 waves). WG=(bg,ns): rows
// bg*16..+16, h-cols ns*32..+32, 4 gates. Wave = (gate g = w&3, khalf = w>>2)
// computes BOTH 16-col tiles of gate g over K-half (640). B-frags = 40 x
// s16x8 = 160 VGPR, PINNED via inline asm so the compiler cannot re-load
// them inside the loop (round-6 failure). K-partials summed via gex2.
// ---------------------------------------------------------------------------
__global__ __launch_bounds__(512, 2) void lstm_persist(
    const unsigned short* __restrict__ xb,   // [B][S][INDIM] bf16
    const unsigned short* __restrict__ WT,   // [NGATE][KTOT] bf16
    unsigned short* __restrict__ h0,         // [B][HID] bf16 (zeroed)
    unsigned short* __restrict__ h1,         // [B][HID] bf16 (zeroed)
    unsigned int* __restrict__ flags,        // [256*8] x 16 uints (zeroed)
    const float* __restrict__ bias) {        // [NGATE]

    __shared__ unsigned short xbuf0[XKK * 512];   // 8 KB, swizzled slots
    __shared__ unsigned short xbuf1[XKK * 512];   // 8 KB
    __shared__ unsigned short hbuf[HKK * 512];    // 32 KB, swizzled slots
    __shared__ float gex2[2 * 4 * ROWS * JCOLS];  // 16 KB: [kh][g][row][col]

    const int tid  = threadIdx.x;
    const int wave = tid >> 6, lane = tid & 63;
    const int lr = lane & 15, kq = lane >> 4;
    const int bg = blockIdx.x & 7;
    const int ns = blockIdx.x >> 3;
    const int b0 = bg * ROWS;
    const int j0 = ns * JCOLS;
    const int g  = wave & 3;     // gate
    const int kh = wave >> 2;    // K-half

    // ---- B fragments, K-half only: br[0..3]=x-part, br[4..19]=h-part ----
    // kh=0: x kk 0..3,  h slices 0..15  (global kk 8..23)
    // kh=1: x kk 4..7,  h slices 16..31 (global kk 24..39)
    s16x8 br0[20], br1[20];
    {
        const unsigned short* bb0 =
            WT + ((size_t)(g * HID + j0 + lr)) * KTOT + kq * 8;
        const unsigned short* bb1 = bb0 + (size_t)16 * KTOT;
        const int xo = kh * 4, ho = kh ? 24 : 8;
#pragma unroll
        for (int i = 0; i < 4; i++) {
            br0[i] = *reinterpret_cast<const s16x8*>(bb0 + (xo + i) * 32);
            br1[i] = *reinterpret_cast<const s16x8*>(bb1 + (xo + i) * 32);
        }
#pragma unroll
        for (int i = 0; i < 16; i++) {
            br0[4 + i] = *reinterpret_cast<const s16x8*>(bb0 + (ho + i) * 32);
            br1[4 + i] = *reinterpret_cast<const s16x8*>(bb1 + (ho + i) * 32);
        }
    }
    // ---- PIN: make values opaque -> compiler cannot re-load from WT ----
#pragma unroll
    for (int i = 0; i < 20; i++) {
        asm volatile("" : "+v"(br0[i]));
        asm volatile("" : "+v"(br1[i]));
    }

    // ---- epilogue constants: 512 threads, 1 cell each ----
    const int erow = tid >> 5, ecol = tid & 31;
    const int j = j0 + ecol;
    const float bf_ = bias[0 * HID + j], bi_ = bias[1 * HID + j],
                bg_ = bias[2 * HID + j], bo_ = bias[3 * HID + j];
    float c = 0.f;

    // ---- x staging: wave stages slice kk=wave (linear dest, inv-swz src) ----
    const int srow = lane >> 2;
    const int skq = ((lane & 3) - ((lane >> 3) & 3)) & 3;
    const unsigned short* xsrc =
        xb + (size_t)(b0 + srow) * SEQ * INDIM + wave * 32 + skq * 8;

    // ---- MFMA A-read slot for lane (lr,kq) ----
    const int p_l = lr * 4 + ((kq + (lr >> 1)) & 3);

    // ---- h load/scatter: wave covers slices 4w..4w+3 ----
    const int hsl = 4 * wave + (lane >> 4);   // slice (== producer ns)
    const int hsub = lane & 15;               // row within slice
    const size_t hsrcoff = (size_t)(b0 + hsub) * HID + hsl * 32;  // shorts

    // ---- flags: mine; poll = producers 4w..4w+3 x 8 wave-flags (lanes<32) --
    unsigned int* wflag = flags + ((size_t)(bg * NSL + ns) * 8 + wave) * 16;
    const unsigned int* pflag =
        flags + ((size_t)(bg * NSL + 4 * wave + ((lane >> 3) & 3)) * 8 + (lane & 7)) * 16;

    // ---- prologue: stage x for t=0 ----
    __builtin_amdgcn_global_load_lds(
        (const __attribute__((address_space(1))) void*)xsrc,
        (__attribute__((address_space(3))) void*)(xbuf0 + wave * 512), 16, 0, 0);
    __syncthreads();

    for (int t = 0; t < SEQ; t++) {
        const unsigned short* hin = (t & 1) ? h1 : h0;
        unsigned short* hout      = (t & 1) ? h0 : h1;
        unsigned short* xcur      = (t & 1) ? xbuf1 : xbuf0;
        unsigned short* xnxt      = (t & 1) ? xbuf0 : xbuf1;

        // ---- per-wave poll: my 4 producers' 8 wave-flags >= t ----
        if (t > 0) {
            for (;;) {
                unsigned v = 0xFFFFFFFFu;
                if (lane < 32)
                    v = __hip_atomic_load(pflag, __ATOMIC_RELAXED,
                                          __HIP_MEMORY_SCOPE_AGENT);
                if (__all((int)(v >= (unsigned)t))) break;
                __builtin_amdgcn_s_sleep(1);
            }
        }

        // ---- issue h loads (latency hidden under x-MFMA) ----
        unsigned long long hv[8];
        {
            const unsigned long long* src =
                (const unsigned long long*)(hin + hsrcoff);
#pragma unroll
            for (int i = 0; i < 8; i++)
                hv[i] = __hip_atomic_load(src + i, __ATOMIC_RELAXED,
                                          __HIP_MEMORY_SCOPE_AGENT);
        }

        // ---- x-part MFMA: kh=0 -> xbuf slices 0..3, kh=1 -> slices 4..7 ----
        f32x4 acc0 = {0.f, 0.f, 0.f, 0.f};
        f32x4 acc1 = {0.f, 0.f, 0.f, 0.f};
        {
            const unsigned short* ax = xcur + p_l * 8 + kh * 4 * 512;
#pragma unroll
            for (int i = 0; i < 4; i++) {
                s16x8 a = *reinterpret_cast<const s16x8*>(ax + i * 512);
                acc0 = __builtin_amdgcn_mfma_f32_16x16x32_bf16(a, br0[i], acc0, 0, 0, 0);
                acc1 = __builtin_amdgcn_mfma_f32_16x16x32_bf16(a, br1[i], acc1, 0, 0, 0);
            }
        }

        // ---- fire-and-forget: stage x for t+1 ----
        if (t + 1 < SEQ) {
            __builtin_amdgcn_global_load_lds(
                (const __attribute__((address_space(1))) void*)(xsrc + (size_t)(t + 1) * INDIM),
                (__attribute__((address_space(3))) void*)(xnxt + wave * 512), 16, 0, 0);
        }

        // ---- scatter h to swizzled LDS slots ----
#pragma unroll
        for (int i = 0; i < 8; i++) {
            int kqi = i >> 1;
            int p = hsub * 4 + ((kqi + (hsub >> 1)) & 3);
            *(unsigned long long*)(hbuf + hsl * 512 + p * 8 + (i & 1) * 4) = hv[i];
        }
        __syncthreads();   // B2: hbuf + x stage complete

        // ---- h-part MFMA: kh=0 -> slices 0..15, kh=1 -> slices 16..31 ----
        {
            const unsigned short* ah = hbuf + p_l * 8 + kh * 16 * 512;
#pragma unroll
            for (int i = 0; i < 16; i++) {
                s16x8 a = *reinterpret_cast<const s16x8*>(ah + i * 512);
                acc0 = __builtin_amdgcn_mfma_f32_16x16x32_bf16(a, br0[4 + i], acc0, 0, 0, 0);
                acc1 = __builtin_amdgcn_mfma_f32_16x16x32_bf16(a, br1[4 + i], acc1, 0, 0, 0);
            }
        }

        // ---- K-partials to gex2 (C/D: col=lane&15, row=(lane>>4)*4+r) ----
        {
            float* gx = gex2 + (size_t)(kh * 4 + g) * 512;
#pragma unroll
            for (int r = 0; r < 4; r++) {
                gx[(kq * 4 + r) * 32 + lr]      = acc0[r];
                gx[(kq * 4 + r) * 32 + 16 + lr] = acc1[r];
            }
        }
        __syncthreads();   // B3: gex2 ready

        // ---- activations + c update + h store (1 cell/thread) ----
        {
            const int cellb = erow * 32 + ecol;
            float gf = gex2[0 * 512 + cellb] + gex2[(4 + 0) * 512 + cellb] + bf_;
            float gi = gex2[1 * 512 + cellb] + gex2[(4 + 1) * 512 + cellb] + bi_;
            float gg = gex2[2 * 512 + cellb] + gex2[(4 + 2) * 512 + cellb] + bg_;
            float go = gex2[3 * 512 + cellb] + gex2[(4 + 3) * 512 + cellb] + bo_;
            float ff = sigmoidf_(gf);
            float ii = sigmoidf_(gi);
            float g2 = tanhf_(gg);
            float oo = sigmoidf_(go);
            c = ff * c + ii * g2;
            unsigned short hvs = f2bf(oo * tanhf_(c));
            __hip_atomic_store(hout + (size_t)(b0 + erow) * HID + j, hvs,
                               __ATOMIC_RELAXED, __HIP_MEMORY_SCOPE_AGENT);
        }

        // ---- per-wave publish: drain own stores, then wave-flag = t+1 ----
        asm volatile("s_waitcnt vmcnt(0)" ::: "memory");
        if (lane == 0)
            __hip_atomic_store(wflag, (unsigned)(t + 1), __ATOMIC_RELAXED,
                               __HIP_MEMORY_SCOPE_AGENT);
    }
}

// ---------------------------------------------------------------------------
// Final FC
// ---------------------------------------------------------------------------
__global__ __launch_bounds__(256) void final_fc(const unsigned short* __restrict__ h,
                                                const float* __restrict__ Wfc,
                                                const float* __restrict__ bfc,
                                                float* __restrict__ out) {
    int b = blockIdx.x;
    int o = threadIdx.x;
    const unsigned short* hr = h + (size_t)b * HID;
    float acc = bfc[o];
#pragma unroll 8
    for (int k = 0; k < HID; k++) {
        acc += __uint_as_float(((unsigned)hr[k]) << 16) * Wfc[(size_t)k * OUTD + o];
    }
    out[(size_t)b * OUTD + o] = acc;
}

// ---------------------------------------------------------------------------
extern "C" void kernel_launch(void* const* d_in, const int* in_sizes, int n_in,
                              void* d_out, int out_size, void* d_ws, size_t ws_size,
                              hipStream_t stream) {
    const float* x    = (const float*)d_in[0];
    const float* Wx   = (const float*)d_in[1];
    const float* Wh   = (const float*)d_in[2];
    const float* bias = (const float*)d_in[3];
    const float* Wfc  = (const float*)d_in[4];
    const float* bfc  = (const float*)d_in[5];
    float* out = (float*)d_out;

    char* ws = (char*)d_ws;
    // ws layout (bytes):
    //   WT    : 4096*1280*2    = 10,485,760  @ 0
    //   xb    : 128*1024*256*2 = 67,108,864  @ 10,485,760
    //   h0    : 128*1024*2     =    262,144  @ 77,594,624
    //   h1    : 128*1024*2     =    262,144  @ 77,856,768
    //   flags : 32768*4        =    131,072  @ 78,118,912  -> 78,249,984 total
    unsigned short* WT  = (unsigned short*)(ws);
    unsigned short* xb  = (unsigned short*)(ws + 10485760);
    unsigned short* h0  = (unsigned short*)(ws + 77594624);
    unsigned short* h1  = (unsigned short*)(ws + 77856768);
    unsigned int* flags = (unsigned int*)(ws + 78118912);

    hipLaunchKernelGGL(prep_wt, dim3(KTOT / 64, NGATE / 64), dim3(256), 0, stream,
                       Wx, Wh, WT);
    hipLaunchKernelGGL(prep_x, dim3(1024), dim3(256), 0, stream, x, xb, h0, h1, flags);

    hipLaunchKernelGGL(lstm_persist, dim3(256), dim3(512), 0, stream,
                       xb, WT, h0, h1, flags, bias);

    // 1024 steps -> final h lands in h0
    hipLaunchKernelGGL(final_fc, dim3(128), dim3(256), 0, stream, h0, Wfc, bfc, out);
}

// Round 9
// 5333.316 us; speedup vs baseline: 1.1069x; 1.1069x over previous
//
#include <hip/hip_runtime.h>
#include <hip/hip_bf16.h>

#define BATCH 128
#define SEQ   1024
#define INDIM 256
#define HID   1024
#define NGATE 4096   // 4*HID
#define KTOT  1280   // INDIM + HID
#define OUTD  256
#define NKK   40     // total K-steps of 32 (1280/32)
#define XKK   8      // k-steps covering the x part (256/32)
#define HKK   32     // k-steps covering the h part
#define NBG   8      // batch groups
#define ROWS  16     // batch rows per group
#define NSL   32     // WGs per group
#define JCOLS 32     // h-columns per WG

typedef __attribute__((ext_vector_type(8))) short s16x8;
typedef __attribute__((ext_vector_type(4))) float f32x4;

__device__ __forceinline__ unsigned short f2bf(float f) {
    unsigned int u = __float_as_uint(f);
    u += 0x7FFFu + ((u >> 16) & 1u);
    return (unsigned short)(u >> 16);
}
__device__ __forceinline__ float sigmoidf_(float x) {
    return 1.0f / (1.0f + __expf(-x));
}
__device__ __forceinline__ float tanhf_(float x) {
    return 1.0f - 2.0f / (1.0f + __expf(2.0f * x));
}

// ---------------------------------------------------------------------------
// Prep 1: WT[n][k] bf16 (transposed, concatenated [Wx;Wh])
// ---------------------------------------------------------------------------
__global__ __launch_bounds__(256) void prep_wt(const float* __restrict__ Wx,
                                               const float* __restrict__ Wh,
                                               unsigned short* __restrict__ WT) {
    __shared__ float tile[64][65];
    int k0 = blockIdx.x * 64;
    int n0 = blockIdx.y * 64;
    for (int idx = threadIdx.x; idx < 64 * 64; idx += 256) {
        int kk = idx >> 6, nn = idx & 63;
        int k = k0 + kk;
        float v = (k < INDIM) ? Wx[(size_t)k * NGATE + (n0 + nn)]
                              : Wh[(size_t)(k - INDIM) * NGATE + (n0 + nn)];
        tile[kk][nn] = v;
    }
    __syncthreads();
    for (int idx = threadIdx.x; idx < 64 * 64; idx += 256) {
        int nn = idx >> 6, kk = idx & 63;
        WT[(size_t)(n0 + nn) * KTOT + (k0 + kk)] = f2bf(tile[kk][nn]);
    }
}

// ---------------------------------------------------------------------------
// Prep 2: x fp32 -> bf16; zero h0/h1; zero per-wave flags.
// ---------------------------------------------------------------------------
__global__ __launch_bounds__(256) void prep_x(const float* __restrict__ x,
                                              unsigned short* __restrict__ xb,
                                              unsigned short* __restrict__ h0,
                                              unsigned short* __restrict__ h1,
                                              unsigned int* __restrict__ flags) {
    int gid = blockIdx.x * blockDim.x + threadIdx.x;
    int stride = gridDim.x * blockDim.x;
    const int N4 = BATCH * SEQ * INDIM / 4;
    const float4* xv = reinterpret_cast<const float4*>(x);
    uint2* xo = reinterpret_cast<uint2*>(xb);
    for (int i = gid; i < N4; i += stride) {
        float4 v = xv[i];
        uint2 o;
        o.x = (unsigned)f2bf(v.x) | ((unsigned)f2bf(v.y) << 16);
        o.y = (unsigned)f2bf(v.z) | ((unsigned)f2bf(v.w) << 16);
        xo[i] = o;
    }
    const int NH = BATCH * HID;
    for (int i = gid; i < NH; i += stride) {
        h0[i] = 0;
        h1[i] = 0;
    }
    // flags: 256 WG x 8 waves x 16 uints (64B padded) = 32768 uints
    for (int i = gid; i < 32768; i += stride) flags[i] = 0;
}

// ---------------------------------------------------------------------------
// Persistent LSTM: 256 WGs x 512 threads (8 waves).
// Logical WG=(bg,ns): rows bg*16..+16, h-cols ns*32..+32, 4 gates.
// PHYSICAL remap (round-robin block->XCD assumed): XCD r hosts ns in
// {4r..4r+3} x all 8 bg -> per-XCD weight working set = 1.31 MB (L2-fits,
// 8 WGs share each slice). Wave = (gate g = w&3, khalf = w>>2) computes
// both 16-col tiles of gate g over its K-half (640).
// B-frags = 40 x s16x8 = 160 regs pinned to AGPRs ("+a" asm); MFMA via
// INTRINSIC so the compiler handles all MAI hazards (round-8 lesson).
// ---------------------------------------------------------------------------
__global__ __launch_bounds__(512, 2) void lstm_persist(
    const unsigned short* __restrict__ xb,   // [B][S][INDIM] bf16
    const unsigned short* __restrict__ WT,   // [NGATE][KTOT] bf16
    unsigned short* __restrict__ h0,         // [B][HID] bf16 (zeroed)
    unsigned short* __restrict__ h1,         // [B][HID] bf16 (zeroed)
    unsigned int* __restrict__ flags,        // [256*8] x 16 uints (zeroed)
    const float* __restrict__ bias) {        // [NGATE]

    __shared__ unsigned short xbuf0[XKK * 512];   // 8 KB, swizzled slots
    __shared__ unsigned short xbuf1[XKK * 512];   // 8 KB
    __shared__ unsigned short hbuf[HKK * 512];    // 32 KB, swizzled slots
    __shared__ float gex2[2 * 4 * ROWS * JCOLS];  // 16 KB: [kh][g][row][col]

    const int tid  = threadIdx.x;
    const int wave = tid >> 6, lane = tid & 63;
    const int lr = lane & 15, kq = lane >> 4;
    // ---- XCD-aware remap: r = physical XCD (round-robin), 4 ns-slices/XCD
    const int r_ = blockIdx.x & 7, q_ = blockIdx.x >> 3;
    const int bg = q_ >> 2;            // 0..7 batch group
    const int ns = r_ * 4 + (q_ & 3);  // 0..31 column slice
    const int b0 = bg * ROWS;
    const int j0 = ns * JCOLS;
    const int g  = wave & 3;     // gate
    const int kh = wave >> 2;    // K-half

    // ---- B fragments, K-half only: [0..3]=x-part, [4..19]=h-part ----
    // kh=0: x kk 0..3,  h slices 0..15  (global kk 8..23)
    // kh=1: x kk 4..7,  h slices 16..31 (global kk 24..39)
    s16x8 br0[20], br1[20];
    {
        const unsigned short* bb0 =
            WT + ((size_t)(g * HID + j0 + lr)) * KTOT + kq * 8;
        const unsigned short* bb1 = bb0 + (size_t)16 * KTOT;
        const int xo = kh * 4, ho = kh ? 24 : 8;
#pragma unroll
        for (int i = 0; i < 4; i++) {
            br0[i] = *reinterpret_cast<const s16x8*>(bb0 + (xo + i) * 32);
            br1[i] = *reinterpret_cast<const s16x8*>(bb1 + (xo + i) * 32);
        }
#pragma unroll
        for (int i = 0; i < 16; i++) {
            br0[4 + i] = *reinterpret_cast<const s16x8*>(bb0 + (ho + i) * 32);
            br1[4 + i] = *reinterpret_cast<const s16x8*>(bb1 + (ho + i) * 32);
        }
    }
    // ---- pin to AGPR file (intrinsic MFMA consumes AV class directly) ----
#pragma unroll
    for (int i = 0; i < 20; i++) {
        asm volatile("" : "+a"(br0[i]));
        asm volatile("" : "+a"(br1[i]));
    }

    // ---- epilogue constants: 512 threads, 1 cell each ----
    const int erow = tid >> 5, ecol = tid & 31;
    const int j = j0 + ecol;
    const float bf_ = bias[0 * HID + j], bi_ = bias[1 * HID + j],
                bg_ = bias[2 * HID + j], bo_ = bias[3 * HID + j];
    float c = 0.f;

    // ---- x staging: wave stages slice kk=wave (linear dest, inv-swz src) ----
    const int srow = lane >> 2;
    const int skq = ((lane & 3) - ((lane >> 3) & 3)) & 3;
    const unsigned short* xsrc =
        xb + (size_t)(b0 + srow) * SEQ * INDIM + wave * 32 + skq * 8;

    // ---- MFMA A-read slot for lane (lr,kq) ----
    const int p_l = lr * 4 + ((kq + (lr >> 1)) & 3);

    // ---- h load/scatter: wave covers slices 4w..4w+3 ----
    const int hsl = 4 * wave + (lane >> 4);   // slice (== producer ns)
    const int hsub = lane & 15;               // row within slice
    const size_t hsrcoff = (size_t)(b0 + hsub) * HID + hsl * 32;  // shorts

    // ---- flags: mine; poll = producers 4w..4w+3 x 8 wave-flags (lanes<32) --
    unsigned int* wflag = flags + ((size_t)(bg * NSL + ns) * 8 + wave) * 16;
    const unsigned int* pflag =
        flags + ((size_t)(bg * NSL + 4 * wave + ((lane >> 3) & 3)) * 8 + (lane & 7)) * 16;

    // ---- prologue: stage x for t=0 ----
    __builtin_amdgcn_global_load_lds(
        (const __attribute__((address_space(1))) void*)xsrc,
        (__attribute__((address_space(3))) void*)(xbuf0 + wave * 512), 16, 0, 0);
    __syncthreads();

    for (int t = 0; t < SEQ; t++) {
        const unsigned short* hin = (t & 1) ? h1 : h0;
        unsigned short* hout      = (t & 1) ? h0 : h1;
        unsigned short* xcur      = (t & 1) ? xbuf1 : xbuf0;
        unsigned short* xnxt      = (t & 1) ? xbuf0 : xbuf1;

        // ---- per-wave poll: my 4 producers' 8 wave-flags >= t ----
        if (t > 0) {
            for (;;) {
                unsigned v = 0xFFFFFFFFu;
                if (lane < 32)
                    v = __hip_atomic_load(pflag, __ATOMIC_RELAXED,
                                          __HIP_MEMORY_SCOPE_AGENT);
                if (__all((int)(v >= (unsigned)t))) break;
                __builtin_amdgcn_s_sleep(1);
            }
        }

        // ---- issue h loads (latency hidden under x-MFMA) ----
        unsigned long long hv[8];
        {
            const unsigned long long* src =
                (const unsigned long long*)(hin + hsrcoff);
#pragma unroll
            for (int i = 0; i < 8; i++)
                hv[i] = __hip_atomic_load(src + i, __ATOMIC_RELAXED,
                                          __HIP_MEMORY_SCOPE_AGENT);
        }

        // ---- x-part MFMA: kh=0 -> xbuf slices 0..3, kh=1 -> slices 4..7 ----
        f32x4 acc0 = {0.f, 0.f, 0.f, 0.f};
        f32x4 acc1 = {0.f, 0.f, 0.f, 0.f};
        {
            const unsigned short* ax = xcur + p_l * 8 + kh * 4 * 512;
#pragma unroll
            for (int i = 0; i < 4; i++) {
                s16x8 a = *reinterpret_cast<const s16x8*>(ax + i * 512);
                acc0 = __builtin_amdgcn_mfma_f32_16x16x32_bf16(a, br0[i], acc0, 0, 0, 0);
                acc1 = __builtin_amdgcn_mfma_f32_16x16x32_bf16(a, br1[i], acc1, 0, 0, 0);
            }
        }

        // ---- fire-and-forget: stage x for t+1 ----
        if (t + 1 < SEQ) {
            __builtin_amdgcn_global_load_lds(
                (const __attribute__((address_space(1))) void*)(xsrc + (size_t)(t + 1) * INDIM),
                (__attribute__((address_space(3))) void*)(xnxt + wave * 512), 16, 0, 0);
        }

        // ---- scatter h to swizzled LDS slots ----
#pragma unroll
        for (int i = 0; i < 8; i++) {
            int kqi = i >> 1;
            int p = hsub * 4 + ((kqi + (hsub >> 1)) & 3);
            *(unsigned long long*)(hbuf + hsl * 512 + p * 8 + (i & 1) * 4) = hv[i];
        }
        __syncthreads();   // B2: hbuf + x stage complete

        // ---- h-part MFMA: kh=0 -> slices 0..15, kh=1 -> slices 16..31 ----
        {
            const unsigned short* ah = hbuf + p_l * 8 + kh * 16 * 512;
#pragma unroll
            for (int i = 0; i < 16; i++) {
                s16x8 a = *reinterpret_cast<const s16x8*>(ah + i * 512);
                acc0 = __builtin_amdgcn_mfma_f32_16x16x32_bf16(a, br0[4 + i], acc0, 0, 0, 0);
                acc1 = __builtin_amdgcn_mfma_f32_16x16x32_bf16(a, br1[4 + i], acc1, 0, 0, 0);
            }
        }

        // ---- K-partials to gex2 (C/D: col=lane&15, row=(lane>>4)*4+r) ----
        {
            float* gx = gex2 + (size_t)(kh * 4 + g) * 512;
#pragma unroll
            for (int rr = 0; rr < 4; rr++) {
                gx[(kq * 4 + rr) * 32 + lr]      = acc0[rr];
                gx[(kq * 4 + rr) * 32 + 16 + lr] = acc1[rr];
            }
        }
        __syncthreads();   // B3: gex2 ready

        // ---- activations + c update + h store (1 cell/thread) ----
        {
            const int cellb = erow * 32 + ecol;
            float gf = gex2[0 * 512 + cellb] + gex2[(4 + 0) * 512 + cellb] + bf_;
            float gi = gex2[1 * 512 + cellb] + gex2[(4 + 1) * 512 + cellb] + bi_;
            float gg = gex2[2 * 512 + cellb] + gex2[(4 + 2) * 512 + cellb] + bg_;
            float go = gex2[3 * 512 + cellb] + gex2[(4 + 3) * 512 + cellb] + bo_;
            float ff = sigmoidf_(gf);
            float ii = sigmoidf_(gi);
            float g2 = tanhf_(gg);
            float oo = sigmoidf_(go);
            c = ff * c + ii * g2;
            unsigned short hvs = f2bf(oo * tanhf_(c));
            __hip_atomic_store(hout + (size_t)(b0 + erow) * HID + j, hvs,
                               __ATOMIC_RELAXED, __HIP_MEMORY_SCOPE_AGENT);
        }

        // ---- per-wave publish: drain own stores, then wave-flag = t+1 ----
        asm volatile("s_waitcnt vmcnt(0)" ::: "memory");
        if (lane == 0)
            __hip_atomic_store(wflag, (unsigned)(t + 1), __ATOMIC_RELAXED,
                               __HIP_MEMORY_SCOPE_AGENT);
    }
}

// ---------------------------------------------------------------------------
// Final FC
// ---------------------------------------------------------------------------
__global__ __launch_bounds__(256) void final_fc(const unsigned short* __restrict__ h,
                                                const float* __restrict__ Wfc,
                                                const float* __restrict__ bfc,
                                                float* __restrict__ out) {
    int b = blockIdx.x;
    int o = threadIdx.x;
    const unsigned short* hr = h + (size_t)b * HID;
    float acc = bfc[o];
#pragma unroll 8
    for (int k = 0; k < HID; k++) {
        acc += __uint_as_float(((unsigned)hr[k]) << 16) * Wfc[(size_t)k * OUTD + o];
    }
    out[(size_t)b * OUTD + o] = acc;
}

// ---------------------------------------------------------------------------
extern "C" void kernel_launch(void* const* d_in, const int* in_sizes, int n_in,
                              void* d_out, int out_size, void* d_ws, size_t ws_size,
                              hipStream_t stream) {
    const float* x    = (const float*)d_in[0];
    const float* Wx   = (const float*)d_in[1];
    const float* Wh   = (const float*)d_in[2];
    const float* bias = (const float*)d_in[3];
    const float* Wfc  = (const float*)d_in[4];
    const float* bfc  = (const float*)d_in[5];
    float* out = (float*)d_out;

    char* ws = (char*)d_ws;
    // ws layout (bytes):
    //   WT    : 4096*1280*2    = 10,485,760  @ 0
    //   xb    : 128*1024*256*2 = 67,108,864  @ 10,485,760
    //   h0    : 128*1024*2     =    262,144  @ 77,594,624
    //   h1    : 128*1024*2     =    262,144  @ 77,856,768
    //   flags : 32768*4        =    131,072  @ 78,118,912  -> 78,249,984 total
    unsigned short* WT  = (unsigned short*)(ws);
    unsigned short* xb  = (unsigned short*)(ws + 10485760);
    unsigned short* h0  = (unsigned short*)(ws + 77594624);
    unsigned short* h1  = (unsigned short*)(ws + 77856768);
    unsigned int* flags = (unsigned int*)(ws + 78118912);

    hipLaunchKernelGGL(prep_wt, dim3(KTOT / 64, NGATE / 64), dim3(256), 0, stream,
                       Wx, Wh, WT);
    hipLaunchKernelGGL(prep_x, dim3(1024), dim3(256), 0, stream, x, xb, h0, h1, flags);

    hipLaunchKernelGGL(lstm_persist, dim3(256), dim3(512), 0, stream,
                       xb, WT, h0, h1, flags, bias);

    // 1024 steps -> final h lands in h0
    hipLaunchKernelGGL(final_fc, dim3(128), dim3(256), 0, stream, h0, Wfc, bfc, out);
}

// Round 10
// 3651.857 us; speedup vs baseline: 1.6165x; 1.4604x over previous
//
#include <hip/hip_runtime.h>
#include <hip/hip_bf16.h>

#define BATCH 128
#define SEQ   1024
#define INDIM 256
#define HID   1024
#define NGATE 4096   // 4*HID
#define KTOT  1280   // INDIM + HID
#define OUTD  256
#define NKK   40     // total K-steps of 32 (1280/32)
#define XKK   8      // k-steps covering the x part (256/32)
#define HKK   32     // k-steps covering the h part
#define NBG   8      // batch groups
#define ROWS  16     // batch rows per group
#define NSL   32     // WGs per group
#define JCOLS 32     // h-columns per WG

typedef __attribute__((ext_vector_type(8))) short s16x8;
typedef __attribute__((ext_vector_type(4))) float f32x4;

__device__ __forceinline__ unsigned short f2bf(float f) {
    unsigned int u = __float_as_uint(f);
    u += 0x7FFFu + ((u >> 16) & 1u);
    return (unsigned short)(u >> 16);
}
__device__ __forceinline__ float sigmoidf_(float x) {
    return 1.0f / (1.0f + __expf(-x));
}
__device__ __forceinline__ float tanhf_(float x) {
    return 1.0f - 2.0f / (1.0f + __expf(2.0f * x));
}

// LDS slot swizzle: slice holds 16 rows x 4 kq of 16B. slot p for (row,kq):
//   p = row*4 + ((kq + (row>>1)) & 3)   -> MFMA b128 reads are ~2-way (free)
// inverse (staging lane s writes slot s): row = s>>2, kq = ((s&3)-(s>>3))&3

// ---------------------------------------------------------------------------
// Prep 1: WT[n][k] bf16 (transposed, concatenated [Wx;Wh])
// ---------------------------------------------------------------------------
__global__ __launch_bounds__(256) void prep_wt(const float* __restrict__ Wx,
                                               const float* __restrict__ Wh,
                                               unsigned short* __restrict__ WT) {
    __shared__ float tile[64][65];
    int k0 = blockIdx.x * 64;
    int n0 = blockIdx.y * 64;
    for (int idx = threadIdx.x; idx < 64 * 64; idx += 256) {
        int kk = idx >> 6, nn = idx & 63;
        int k = k0 + kk;
        float v = (k < INDIM) ? Wx[(size_t)k * NGATE + (n0 + nn)]
                              : Wh[(size_t)(k - INDIM) * NGATE + (n0 + nn)];
        tile[kk][nn] = v;
    }
    __syncthreads();
    for (int idx = threadIdx.x; idx < 64 * 64; idx += 256) {
        int nn = idx >> 6, kk = idx & 63;
        WT[(size_t)(n0 + nn) * KTOT + (k0 + kk)] = f2bf(tile[kk][nn]);
    }
}

// ---------------------------------------------------------------------------
// Prep 2: x fp32 -> bf16, zero h0, zero flags
// ---------------------------------------------------------------------------
__global__ __launch_bounds__(256) void prep_x(const float* __restrict__ x,
                                              unsigned short* __restrict__ xb,
                                              unsigned short* __restrict__ h0,
                                              unsigned int* __restrict__ flags) {
    int gid = blockIdx.x * blockDim.x + threadIdx.x;
    int stride = gridDim.x * blockDim.x;
    const int N4 = BATCH * SEQ * INDIM / 4;
    const float4* xv = reinterpret_cast<const float4*>(x);
    uint2* xo = reinterpret_cast<uint2*>(xb);
    for (int i = gid; i < N4; i += stride) {
        float4 v = xv[i];
        uint2 o;
        o.x = (unsigned)f2bf(v.x) | ((unsigned)f2bf(v.y) << 16);
        o.y = (unsigned)f2bf(v.z) | ((unsigned)f2bf(v.w) << 16);
        xo[i] = o;
    }
    const int NH = BATCH * HID;
    for (int i = gid; i < NH; i += stride) h0[i] = 0;
    for (int i = gid; i < 256 * 64; i += stride) flags[i] = 0;  // 256 slots x 256B
}

// ---------------------------------------------------------------------------
// Persistent LSTM (round-3 structure, verbatim) + AGPR-pinned weights.
// 256 WGs x 256 thr; WG=(bg,ns): rows bg*16..+16, h-cols ns*32..+32, 4 gates.
// B-fragments: 80 x s16x8 = 320 regs pinned into the AGPR file ("+a" asm);
// at __launch_bounds__(256,1) each wave has 512 regs, so 320 AGPR + ~130
// arch VGPR fits WITHOUT spilling (rounds 3-9: every other config forced
// the allocator to spill/re-load weights each step). MFMA via intrinsic so
// all MAI hazards are compiler-handled.
// ---------------------------------------------------------------------------
__global__ __launch_bounds__(256, 1) void lstm_persist(
    const unsigned short* __restrict__ xb,   // [B][S][INDIM] bf16
    const unsigned short* __restrict__ WT,   // [NGATE][KTOT] bf16
    unsigned short* __restrict__ h0,         // [B][HID] bf16 (zeroed)
    unsigned short* __restrict__ h1,         // [B][HID] bf16
    unsigned int* __restrict__ flags,        // [NBG*NSL] x 64 uints (zeroed)
    const float* __restrict__ bias) {        // [NGATE]

    __shared__ unsigned short xbuf[2][XKK * 512];  // 2 x 8 KB, swizzled slots
    __shared__ unsigned short hbuf[HKK * 512];     // 32 KB, swizzled slots
    __shared__ float gex[4 * ROWS * JCOLS];        // 8 KB

    const int tid  = threadIdx.x;
    const int wave = tid >> 6, lane = tid & 63;
    const int lr = lane & 15, kq = lane >> 4;
    const int bg = blockIdx.x & 7;
    const int ns = blockIdx.x >> 3;
    const int b0 = bg * ROWS;
    const int j0 = ns * JCOLS;

    // ---- B fragments into registers (gate=wave, cols j0..j0+31, full K) ----
    s16x8 b0r[NKK], b1r[NKK];
    {
        const unsigned short* base0 =
            WT + ((size_t)(wave * HID + j0 + lr)) * KTOT + kq * 8;
        const unsigned short* base1 = base0 + (size_t)16 * KTOT;
#pragma unroll
        for (int kk = 0; kk < NKK; kk++) {
            b0r[kk] = *reinterpret_cast<const s16x8*>(base0 + kk * 32);
            b1r[kk] = *reinterpret_cast<const s16x8*>(base1 + kk * 32);
        }
    }
    // ---- PIN all 80 fragments into the AGPR file; at (256,1) the budget
    //      is 512 regs/wave so these CANNOT be spilled-and-reloaded ----
#pragma unroll
    for (int kk = 0; kk < NKK; kk++) {
        asm volatile("" : "+a"(b0r[kk]));
        asm volatile("" : "+a"(b1r[kk]));
    }

    // ---- epilogue constants ----
    const int ecol = tid & 31, erow0 = tid >> 5, erow1 = erow0 + 8;
    const int j = j0 + ecol;
    const float bf = bias[0 * HID + j], bi = bias[1 * HID + j],
                bgg = bias[2 * HID + j], bo = bias[3 * HID + j];
    float c0 = 0.f, c1 = 0.f;

    // ---- staging addressing ----
    const int srow = lane >> 2;
    const int skq = ((lane & 3) - ((lane >> 3) & 3)) & 3;
    const unsigned short* xsrc =
        xb + (size_t)(b0 + srow) * SEQ * INDIM + skq * 8;
    // MFMA A-read slot for this lane
    const int p_l = lr * 4 + ((kq + (lr >> 1)) & 3);

    unsigned int* myflag = flags + (size_t)(bg * NSL + ns) * 64;

    // ---- prologue: stage x for t=0 ----
#pragma unroll
    for (int q = 0; q < 2; q++) {
        int kk = 2 * wave + q;
        __builtin_amdgcn_global_load_lds(
            (const __attribute__((address_space(1))) void*)(xsrc + (size_t)kk * 32),
            (__attribute__((address_space(3))) void*)(&xbuf[0][kk * 512]),
            16, 0, 0);
    }
    __syncthreads();

    for (int t = 0; t < SEQ; t++) {
        const unsigned short* hin = (t & 1) ? h1 : h0;
        unsigned short* hout      = (t & 1) ? h0 : h1;
        const int par = t & 1;

        // ---- x-part MFMA (no dependence on other WGs) ----
        f32x4 acc0 = {0.f, 0.f, 0.f, 0.f};
        f32x4 acc1 = {0.f, 0.f, 0.f, 0.f};
        {
            const unsigned short* ax = &xbuf[par][p_l * 8];
#pragma unroll
            for (int kk = 0; kk < XKK; kk++) {
                s16x8 a = *reinterpret_cast<const s16x8*>(ax + kk * 512);
                acc0 = __builtin_amdgcn_mfma_f32_16x16x32_bf16(a, b0r[kk], acc0, 0, 0, 0);
                acc1 = __builtin_amdgcn_mfma_f32_16x16x32_bf16(a, b1r[kk], acc1, 0, 0, 0);
            }
        }

        // ---- fire-and-forget: stage x for t+1 into other parity buffer ----
        if (t + 1 < SEQ) {
#pragma unroll
            for (int q = 0; q < 2; q++) {
                int kk = 2 * wave + q;
                __builtin_amdgcn_global_load_lds(
                    (const __attribute__((address_space(1))) void*)(xsrc + (size_t)(t + 1) * INDIM + kk * 32),
                    (__attribute__((address_space(3))) void*)(&xbuf[par ^ 1][kk * 512]),
                    16, 0, 0);
            }
        }

        // ---- wait for all 32 producers of this group to publish h_t ----
        if (tid < NSL) {
            const unsigned int* fp = flags + (size_t)(bg * NSL + tid) * 64;
            while (__hip_atomic_load(fp, __ATOMIC_RELAXED,
                                     __HIP_MEMORY_SCOPE_AGENT) < (unsigned)t) {
                __builtin_amdgcn_s_sleep(1);
            }
        }
        asm volatile("" ::: "memory");
        __syncthreads();   // B1: flags satisfied for whole WG

        // ---- coherent h loads (L3) -> swizzled LDS ----
        {
            unsigned long long hv[16];
#pragma unroll
            for (int i = 0; i < 16; i++) {
                int u = tid + 256 * i;
                int kkh = u >> 7, v = u & 127, row = v >> 3, k8 = v & 7;
                const unsigned long long* gp = (const unsigned long long*)
                    (hin + (size_t)(b0 + row) * HID + kkh * 32 + k8 * 4);
                hv[i] = __hip_atomic_load(gp, __ATOMIC_RELAXED,
                                          __HIP_MEMORY_SCOPE_AGENT);
            }
#pragma unroll
            for (int i = 0; i < 16; i++) {
                int u = tid + 256 * i;
                int kkh = u >> 7, v = u & 127, row = v >> 3, k8 = v & 7;
                int kqh = k8 >> 1;
                int p = row * 4 + ((kqh + (row >> 1)) & 3);
                *(unsigned long long*)((char*)hbuf + kkh * 1024 + p * 16 + (k8 & 1) * 8) = hv[i];
            }
        }
        __syncthreads();   // B2: hbuf ready

        // ---- h-part MFMA ----
        {
            const unsigned short* ah = &hbuf[p_l * 8];
#pragma unroll
            for (int kk = 0; kk < HKK; kk++) {
                s16x8 a = *reinterpret_cast<const s16x8*>(ah + kk * 512);
                acc0 = __builtin_amdgcn_mfma_f32_16x16x32_bf16(a, b0r[XKK + kk], acc0, 0, 0, 0);
                acc1 = __builtin_amdgcn_mfma_f32_16x16x32_bf16(a, b1r[XKK + kk], acc1, 0, 0, 0);
            }
        }

        // ---- gate exchange (C/D: col=lane&15, row=(lane>>4)*4+r) ----
#pragma unroll
        for (int r = 0; r < 4; r++) {
            int row = kq * 4 + r;
            gex[wave * 512 + row * 32 + lr]      = acc0[r];
            gex[wave * 512 + row * 32 + 16 + lr] = acc1[r];
        }
        __syncthreads();   // B3: gex ready

        // ---- activations + c update + coherent h stores ----
        {
            float ff = sigmoidf_(gex[0 * 512 + erow0 * 32 + ecol] + bf);
            float ii = sigmoidf_(gex[1 * 512 + erow0 * 32 + ecol] + bi);
            float gg = tanhf_(gex[2 * 512 + erow0 * 32 + ecol] + bgg);
            float oo = sigmoidf_(gex[3 * 512 + erow0 * 32 + ecol] + bo);
            c0 = ff * c0 + ii * gg;
            __hip_atomic_store(hout + (size_t)(b0 + erow0) * HID + j,
                               f2bf(oo * tanhf_(c0)),
                               __ATOMIC_RELAXED, __HIP_MEMORY_SCOPE_AGENT);
        }
        {
            float ff = sigmoidf_(gex[0 * 512 + erow1 * 32 + ecol] + bf);
            float ii = sigmoidf_(gex[1 * 512 + erow1 * 32 + ecol] + bi);
            float gg = tanhf_(gex[2 * 512 + erow1 * 32 + ecol] + bgg);
            float oo = sigmoidf_(gex[3 * 512 + erow1 * 32 + ecol] + bo);
            c1 = ff * c1 + ii * gg;
            __hip_atomic_store(hout + (size_t)(b0 + erow1) * HID + j,
                               f2bf(oo * tanhf_(c1)),
                               __ATOMIC_RELAXED, __HIP_MEMORY_SCOPE_AGENT);
        }

        __syncthreads();   // B4: every wave's stores drained (vmcnt(0)) + gex free
        asm volatile("" ::: "memory");
        if (tid == 0) {
            __hip_atomic_store(myflag, (unsigned)(t + 1),
                               __ATOMIC_RELAXED, __HIP_MEMORY_SCOPE_AGENT);
        }
    }
}

// ---------------------------------------------------------------------------
// Final FC
// ---------------------------------------------------------------------------
__global__ __launch_bounds__(256) void final_fc(const unsigned short* __restrict__ h,
                                                const float* __restrict__ Wfc,
                                                const float* __restrict__ bfc,
                                                float* __restrict__ out) {
    int b = blockIdx.x;
    int o = threadIdx.x;
    const unsigned short* hr = h + (size_t)b * HID;
    float acc = bfc[o];
#pragma unroll 8
    for (int k = 0; k < HID; k++) {
        acc += __uint_as_float(((unsigned)hr[k]) << 16) * Wfc[(size_t)k * OUTD + o];
    }
    out[(size_t)b * OUTD + o] = acc;
}

// ---------------------------------------------------------------------------
extern "C" void kernel_launch(void* const* d_in, const int* in_sizes, int n_in,
                              void* d_out, int out_size, void* d_ws, size_t ws_size,
                              hipStream_t stream) {
    const float* x    = (const float*)d_in[0];
    const float* Wx   = (const float*)d_in[1];
    const float* Wh   = (const float*)d_in[2];
    const float* bias = (const float*)d_in[3];
    const float* Wfc  = (const float*)d_in[4];
    const float* bfc  = (const float*)d_in[5];
    float* out = (float*)d_out;

    char* ws = (char*)d_ws;
    // ws layout (bytes):
    //   WT    : 4096*1280*2    = 10,485,760  @ 0
    //   xb    : 128*1024*256*2 = 67,108,864  @ 10,485,760
    //   h0    : 128*1024*2     =    262,144  @ 77,594,624
    //   h1    : 128*1024*2     =    262,144  @ 77,856,768
    //   flags : 256*64*4       =     65,536  @ 78,118,912
    unsigned short* WT  = (unsigned short*)(ws);
    unsigned short* xb  = (unsigned short*)(ws + 10485760);
    unsigned short* h0  = (unsigned short*)(ws + 77594624);
    unsigned short* h1  = (unsigned short*)(ws + 77856768);
    unsigned int* flags = (unsigned int*)(ws + 78118912);

    hipLaunchKernelGGL(prep_wt, dim3(KTOT / 64, NGATE / 64), dim3(256), 0, stream,
                       Wx, Wh, WT);
    hipLaunchKernelGGL(prep_x, dim3(1024), dim3(256), 0, stream, x, xb, h0, flags);

    hipLaunchKernelGGL(lstm_persist, dim3(256), dim3(256), 0, stream,
                       xb, WT, h0, h1, flags, bias);

    // 1024 steps -> final h lands in h0
    hipLaunchKernelGGL(final_fc, dim3(128), dim3(256), 0, stream, h0, Wfc, bfc, out);
}